// Round 1
// 78.298 us; speedup vs baseline: 1.0116x; 1.0116x over previous
//
#include <hip/hip_runtime.h>
#include <math.h>

// Closed-form reduction of the 4-qubit circuit:
// pair {q0,q1}: RY(d0)RY(t0) q0, RX(t1) q1, CNOT(0,1), RX(t4) q0
//   -> Z0 = cos(t4) cos(d0+t0);  Z1 = cos(t1) cos(d0+t0) cos(d1)
// pair {q2,q3}: RZ(t2) (diagonal, drops), RY(d3)RY(t3) q3, CNOT(2,3), RZ(t5) (drops)
//   -> Z2 = cos(d2);  Z3 = cos(d2) cos(d3+t3)
// d0..d3 = 4 horizontally-adjacent 2x2/stride-2 conv outputs.
//
// R3 structure: one 256-thread block per image (2048 blocks -> 8 blocks/CU,
// 32 waves/CU occupancy). Thread t < 196 owns exactly one patch: 4x float4
// coalesced x-loads, conv, HW-transcendental __cosf (args bounded, ~2 rev),
// 10x float4 W loads (L1-resident). Wave shuffle-reduce + 160B LDS cross-wave
// reduce of the 10 logits; thread 0 does the precise log-softmax tail.

__global__ __launch_bounds__(256) void quanv_fused(
    const float* __restrict__ x,      // [B,1,56,56]
    const float* __restrict__ cw,     // [1,1,2,2]
    const float* __restrict__ theta,  // [6]
    const float* __restrict__ W,      // [10,784]
    const float* __restrict__ bias,   // [10]
    float* __restrict__ out,          // [B,10]
    int B)
{
    const int b    = blockIdx.x;
    const int t    = threadIdx.x;
    const int wave = t >> 6;
    const int lane = t & 63;

    __shared__ float red[4][10];

    float lg[10];
#pragma unroll
    for (int k = 0; k < 10; ++k) lg[k] = 0.f;

    if (t < 196) {
        const float w00 = cw[0], w01 = cw[1], w10 = cw[2], w11 = cw[3];
        const float th0  = theta[0];
        const float cth1 = __cosf(theta[1]);
        const float th3  = theta[3];
        const float cth4 = __cosf(theta[4]);

        const float* xb = x + (size_t)b * 3136;
        const int r  = t / 7;          // conv-output row 0..27
        const int c8 = (t % 7) * 8;    // input col offset
        const float* xr = xb + r * 112 + c8;
        const float4 a0 = *(const float4*)(xr);
        const float4 a1 = *(const float4*)(xr + 4);
        const float4 b0 = *(const float4*)(xr + 56);
        const float4 b1 = *(const float4*)(xr + 60);

        const float d0 = w00*a0.x + w01*a0.y + w10*b0.x + w11*b0.y;
        const float d1 = w00*a0.z + w01*a0.w + w10*b0.z + w11*b0.w;
        const float d2 = w00*a1.x + w01*a1.y + w10*b1.x + w11*b1.y;
        const float d3 = w00*a1.z + w01*a1.w + w10*b1.z + w11*b1.w;

        const float c0 = __cosf(d0 + th0);
        const float m0 = cth4 * c0;
        const float m1 = cth1 * c0 * __cosf(d1);
        const float m2 = __cosf(d2);
        const float m3 = m2 * __cosf(d3 + th3);

        const float* wp = W + t * 4;
#pragma unroll
        for (int k = 0; k < 10; ++k) {
            const float4 wk = *(const float4*)(wp + k * 784);
            lg[k] += m0*wk.x + m1*wk.y + m2*wk.z + m3*wk.w;
        }
    }

    // wave (64-lane) shuffle reduction of the 10 partial logits
#pragma unroll
    for (int off = 32; off >= 1; off >>= 1) {
#pragma unroll
        for (int k = 0; k < 10; ++k)
            lg[k] += __shfl_down(lg[k], off, 64);
    }

    if (lane == 0) {
#pragma unroll
        for (int k = 0; k < 10; ++k) red[wave][k] = lg[k];
    }
    __syncthreads();

    if (t == 0) {
        float v[10];
        float mx = -1e30f;
#pragma unroll
        for (int k = 0; k < 10; ++k) {
            v[k] = red[0][k] + red[1][k] + red[2][k] + red[3][k] + bias[k];
            mx = fmaxf(mx, v[k]);
        }
        float s = 0.f;
#pragma unroll
        for (int k = 0; k < 10; ++k) s += expf(v[k] - mx);
        const float lse = mx + logf(s);
        float* ob = out + (size_t)b * 10;
#pragma unroll
        for (int k = 0; k < 10; ++k) ob[k] = v[k] - lse;
    }
}

extern "C" void kernel_launch(void* const* d_in, const int* in_sizes, int n_in,
                              void* d_out, int out_size, void* d_ws, size_t ws_size,
                              hipStream_t stream) {
    const float* x     = (const float*)d_in[0];
    const float* cw    = (const float*)d_in[1];
    const float* theta = (const float*)d_in[2];
    const float* W     = (const float*)d_in[3];
    const float* bias  = (const float*)d_in[4];
    float* out = (float*)d_out;

    const int B = in_sizes[0] / 3136;   // 2048
    quanv_fused<<<B, 256, 0, stream>>>(x, cw, theta, W, bias, out, B);
}